// Round 15
// baseline (364.222 us; speedup 1.0000x reference)
//
#include <hip/hip_runtime.h>

typedef unsigned short u16;
typedef unsigned int u32;
typedef __attribute__((ext_vector_type(8))) short bf16x8;
typedef __attribute__((ext_vector_type(4))) float f32x4;
typedef __attribute__((ext_vector_type(16))) float f32x16;

#define NB 16
#define NC 256
#define NL 2048
#define EPS 1e-5f
#define QSC2 0.0901684401f   // (1/sqrt(256)) * log2(e)
#define DEFER 11.54f         // 8 * log2(e)
#define TROWS 2050
#define PHALF ((size_t)NB * NC * NL)

__device__ __forceinline__ float bf2f(u16 a) {
  union { unsigned u; float f; } v; v.u = (unsigned)a << 16; return v.f;
}
__device__ __forceinline__ u16 f2bf(float f) {
  union { float f; unsigned u; } v; v.f = f;
  return (u16)((v.u + 0x7fffu + ((v.u >> 16) & 1u)) >> 16);
}
__device__ __forceinline__ u32 cvtpk(float lo, float hi) {
  u32 r;
  asm("v_cvt_pk_bf16_f32 %0, %1, %2" : "=v"(r) : "v"(lo), "v"(hi));
  return r;
}
__device__ __forceinline__ float ex2(float x) {
  float r;
  asm("v_exp_f32 %0, %1" : "=v"(r) : "v"(x));
  return r;
}
__device__ __forceinline__ void gld16(const void* gsrc, void* ldst) {
  __builtin_amdgcn_global_load_lds(
      (const __attribute__((address_space(1))) void*)gsrc,
      (__attribute__((address_space(3))) void*)ldst, 16, 0, 0);
}

// ---------------- weight pack ----------------
__global__ __launch_bounds__(256)
void pack_w(const float* __restrict__ w1, const float* __restrict__ w2,
            const float* __restrict__ w3, const float* __restrict__ w4,
            const float* __restrict__ lw, const float* __restrict__ lb,
            u16* __restrict__ Wp, u16* __restrict__ Wq, float* __restrict__ bq)
{
  const int a = blockIdx.y;
  const int gid = blockIdx.x * 256 + threadIdx.x;
  if (a < 4) {
    const float* w = a == 0 ? w1 : a == 1 ? w2 : a == 2 ? w3 : w4;
    const int d = gid >> 16, rem = gid & 65535;
    const int oc = rem >> 8, ic = rem & 255;
    Wp[a * 196608 + gid] = f2bf(w[(oc * 256 + ic) * 3 + d]);
  } else {
    const int oc = gid >> 8;
    const float s = (oc >= 256 && oc < 512) ? QSC2 : 1.0f;
    Wq[gid] = f2bf(lw[gid] * s);
    if (gid < 768) bq[gid] = lb[gid] * ((gid >= 256 && gid < 512) ? QSC2 : 1.0f);
  }
}

// ---------------- GN stats: fp32 (C,L) -> pstat[b*256+c] ----
__global__ __launch_bounds__(256)
void stats_f32(const float* __restrict__ x, float2* __restrict__ pstat)
{
  const int blk = blockIdx.x;
  const float* p = x + (size_t)blk * NL + threadIdx.x * 8;
  const float4 a = ((const float4*)p)[0];
  const float4 c4 = ((const float4*)p)[1];
  float s = (a.x + a.y) + (a.z + a.w) + (c4.x + c4.y) + (c4.z + c4.w);
  float ss = a.x*a.x + a.y*a.y + a.z*a.z + a.w*a.w + c4.x*c4.x + c4.y*c4.y + c4.z*c4.z + c4.w*c4.w;
#pragma unroll
  for (int o = 32; o > 0; o >>= 1) { s += __shfl_down(s, o); ss += __shfl_down(ss, o); }
  __shared__ float2 red[4];
  if ((threadIdx.x & 63) == 0) red[threadIdx.x >> 6] = make_float2(s, ss);
  __syncthreads();
  if (threadIdx.x == 0)
    pstat[blk] = make_float2(red[0].x + red[1].x + red[2].x + red[3].x,
                             red[0].y + red[1].y + red[2].y + red[3].y);
}

// ---------------- GN apply: fp32 (C,L) -> bf16 T padded (bank-aware transpose) ----
__global__ __launch_bounds__(256)
void apply_f32T(const float* __restrict__ x, const float2* __restrict__ pstat,
                const float* __restrict__ gw, const float* __restrict__ gb,
                u16* __restrict__ outT)
{
  __shared__ float2 chs[256];
  __shared__ float gm[32], gi[32];
  __shared__ float ta[32][257];
  const int t = threadIdx.x, b = blockIdx.y;
  const int L0 = blockIdx.x * 32;
  chs[t] = pstat[b * 256 + t];
  __syncthreads();
  if (t < 32) {
    float S = 0.f, SS = 0.f;
#pragma unroll
    for (int j = 0; j < 8; ++j) { S += chs[t * 8 + j].x; SS += chs[t * 8 + j].y; }
    const float mean = S * (1.f / 16384.f);
    const float var = SS * (1.f / 16384.f) - mean * mean;
    gm[t] = mean; gi[t] = rsqrtf(var + EPS);
  }
  {
    const int cR = t >> 3, lq = (t & 7) * 4;
#pragma unroll
    for (int i = 0; i < 8; ++i) {
      const int c = i * 32 + cR;
      const float4 v = *(const float4*)&x[((size_t)b * NC + c) * NL + L0 + lq];
      ta[lq + 0][c] = v.x; ta[lq + 1][c] = v.y; ta[lq + 2][c] = v.z; ta[lq + 3][c] = v.w;
    }
  }
  __syncthreads();
  const int g = t & 31, rbase = t >> 5;
  float ga[8], be[8];
#pragma unroll
  for (int j = 0; j < 4; ++j)
#pragma unroll
    for (int k = 0; k < 2; ++k) {
      const int c = 2 * g + 64 * j + k;
      const int grp = c >> 3;
      ga[j * 2 + k] = gw[c] * gi[grp];
      be[j * 2 + k] = gb[c] - gm[grp] * ga[j * 2 + k];
    }
#pragma unroll
  for (int ri = 0; ri < 4; ++ri) {
    const int row = rbase + ri * 8;
    u16* orow = outT + ((size_t)b * TROWS + 1 + L0 + row) * 256;
#pragma unroll
    for (int j = 0; j < 4; ++j) {
      const int c = 2 * g + 64 * j;
      const float v0 = ta[row][c], v1 = ta[row][c + 1];
      ushort2 o;
      o.x = f2bf(fmaxf(fmaf(v0, ga[j * 2], be[j * 2]), 0.f));
      o.y = f2bf(fmaxf(fmaf(v1, ga[j * 2 + 1], be[j * 2 + 1]), 0.f));
      *(ushort2*)(orow + c) = o;
    }
  }
  if (blockIdx.x == 0 && t < 128) {
    const int r = (t >> 6) ? 2049 : 0;
    *(ushort4*)(outT + ((size_t)b * TROWS + r) * 256 + (t & 63) * 4) = (ushort4){0, 0, 0, 0};
  }
}

// ---------------- GN apply: bf16 T -> bf16 T padded (16-chunk partial stats) ----------------
__global__ __launch_bounds__(256)
void apply_TT(const u16* __restrict__ inT, const float2* __restrict__ pstat,
              const float* __restrict__ gw, const float* __restrict__ gb,
              u16* __restrict__ outT)
{
  __shared__ float2 chs[256];
  __shared__ float gm[32], gi[32];
  const int t = threadIdx.x, b = blockIdx.y;
  {
    float S = 0.f, SS = 0.f;
#pragma unroll
    for (int p = 0; p < 16; ++p) {
      const float2 v = pstat[((size_t)b * 16 + p) * 256 + t];
      S += v.x; SS += v.y;
    }
    chs[t] = make_float2(S, SS);
  }
  __syncthreads();
  if (t < 32) {
    float S = 0.f, SS = 0.f;
#pragma unroll
    for (int j = 0; j < 8; ++j) { S += chs[t * 8 + j].x; SS += chs[t * 8 + j].y; }
    const float mean = S * (1.f / 16384.f);
    const float var = SS * (1.f / 16384.f) - mean * mean;
    gm[t] = mean; gi[t] = rsqrtf(var + EPS);
  }
  __syncthreads();
  const int g = t & 31;
  float ga[8], be[8];
#pragma unroll
  for (int j = 0; j < 8; ++j) {
    ga[j] = gw[g * 8 + j] * gi[g];
    be[j] = gb[g * 8 + j] - gm[g] * ga[j];
  }
#pragma unroll
  for (int j = 0; j < 16; ++j) {
    const int row = blockIdx.x * 128 + j * 8 + (t >> 5);
    const size_t off = ((size_t)b * TROWS + 1 + row) * 256 + g * 8;
    const bf16x8 h = *(const bf16x8*)(inT + off);
    u16 o[8];
#pragma unroll
    for (int i = 0; i < 8; ++i)
      o[i] = f2bf(fmaxf(fmaf(bf2f(((const u16*)&h)[i]), ga[i], be[i]), 0.f));
    *(bf16x8*)(outT + off) = *(bf16x8*)o;
  }
  if (blockIdx.x == 0 && t < 128) {
    const int r = (t >> 6) ? 2049 : 0;
    *(ushort4*)(outT + ((size_t)b * TROWS + r) * 256 + (t & 63) * 4) = (ushort4){0, 0, 0, 0};
  }
}

// ---------------- conv GEMM via MFMA (3-deep W prefetch, r14) ----------------
template<int OCT, int KD, bool HAS_T, int RESM, bool STATS>
__global__ __launch_bounds__(256, 2)
void conv_mfma(const u16* __restrict__ xT, const u16* __restrict__ Wp,
               const float* __restrict__ bias, const float* __restrict__ tadd,
               u16* __restrict__ outT, u16* __restrict__ vTout,
               const float* __restrict__ resf, const u16* __restrict__ resT,
               float* __restrict__ outf, float2* __restrict__ pstatOut)
{
  constexpr int DOFF = (KD == 3) ? 0 : 1;
  __shared__ __align__(16) u16 xs[2][130 * 128];
  const int bx = blockIdx.x;
  const int b = blockIdx.z;
  int lbx, ocb0, nsub;
  if (OCT == 256) {
    const int wid = (bx & 7) * 4 + (bx >> 3);
    lbx = wid >> 1; ocb0 = (wid & 1) * 128; nsub = 1;
  } else {
    const int wid = (bx & 7) * 8 + (bx >> 3);
    const int yy = wid & 3;
    lbx = wid >> 2;
    if (yy < 2) { ocb0 = yy * 256; nsub = 2; }
    else { ocb0 = 512 + (yy - 2) * 128; nsub = 1; }
  }
  const int lb = lbx * 128;
  const int tid = threadIdx.x;
  const int w = tid >> 6, lane = tid & 63;
  const int l15 = lane & 15, lg = lane >> 4;
  const int woc = (w >> 1) * 64, wl = (w & 1) * 64;

  const u16* xTb = xT + ((size_t)b * TROWS + lb) * 256;

  auto stageX = [&](int buf, int ich) {
    u16* xb = &xs[buf][0];
#pragma unroll
    for (int j = 0; j < 8; ++j) {
      const int slot = w * 512 + j * 64 + lane;
      const int row = slot >> 4, g0 = slot & 15;
      const int g = (g0 & 8) | ((g0 ^ row) & 7);
      gld16(xTb + (size_t)row * 256 + ich * 128 + g * 8, xb + (size_t)(w * 512 + j * 64) * 8);
    }
    if (w == 0 && lane < 32) {
      const int slot = 2048 + lane;
      const int row = slot >> 4, g0 = slot & 15;
      const int g = (g0 & 8) | ((g0 ^ row) & 7);
      gld16(xTb + (size_t)row * 256 + ich * 128 + g * 8, xb + (size_t)2048 * 8);
    }
  };
  auto loadW = [&](bf16x8 (&af)[KD][4], int p, int ocb) {
    const int ich = p >> 2, kc = p & 3;
#pragma unroll
    for (int d = 0; d < KD; ++d)
#pragma unroll
      for (int mf = 0; mf < 4; ++mf)
        af[d][mf] = *(const bf16x8*)(Wp + ((size_t)d * OCT + ocb + woc + mf * 16 + l15) * 256
                                        + ich * 128 + kc * 32 + lg * 8);
  };

  stageX(0, 0);
  __syncthreads();
  stageX(1, 1);

  for (int sidx = 0; sidx < nsub; ++sidx) {
    const int ocb = ocb0 + sidx * 128;
    f32x4 acc[4][4];
#pragma unroll
    for (int i = 0; i < 4; ++i)
#pragma unroll
      for (int j = 0; j < 4; ++j) acc[i][j] = (f32x4){0.f, 0.f, 0.f, 0.f};

    bf16x8 afbuf[3][KD][4];           // 3-deep W prefetch
    loadW(afbuf[0], 0, ocb);
    loadW(afbuf[1], 1, ocb);

#pragma unroll
    for (int p = 0; p < 8; ++p) {
      if (p == 4 && sidx == 0) __syncthreads();
      if (p < 6) loadW(afbuf[(p + 2) % 3], p + 2, ocb);
      const int kc = p & 3;
      const int gg = kc * 4 + lg;
      const char* xb = (const char*)&xs[p >> 2][0];
#pragma unroll
      for (int nf = 0; nf < 4; ++nf) {
#pragma unroll
        for (int d = 0; d < KD; ++d) {
          const int r = wl + nf * 16 + l15 + d + DOFF;
          const int gsr = (gg & 8) | ((gg ^ r) & 7);
          const bf16x8 bf = *(const bf16x8*)(xb + r * 256 + gsr * 16);
#pragma unroll
          for (int mf = 0; mf < 4; ++mf)
            acc[mf][nf] = __builtin_amdgcn_mfma_f32_16x16x32_bf16(afbuf[p % 3][d][mf], bf, acc[mf][nf], 0, 0, 0);
        }
      }
    }

    if (OCT == 768 && ocb0 >= 512) {
      __syncthreads();
      u16* tile = (u16*)&xs[0][0];   // [128][136]
#pragma unroll
      for (int mf = 0; mf < 4; ++mf) {
        const int cl = woc + mf * 16 + lg * 4;
        const float4 bv = *(const float4*)&bias[ocb + cl];
#pragma unroll
        for (int nf = 0; nf < 4; ++nf) {
          const int ll = wl + nf * 16 + l15;
          const f32x4 a = acc[mf][nf];
          tile[(cl + 0) * 136 + ll] = f2bf(a[0] + bv.x);
          tile[(cl + 1) * 136 + ll] = f2bf(a[1] + bv.y);
          tile[(cl + 2) * 136 + ll] = f2bf(a[2] + bv.z);
          tile[(cl + 3) * 136 + ll] = f2bf(a[3] + bv.w);
        }
      }
      __syncthreads();
      const int cv0 = ocb - 512;
#pragma unroll
      for (int it = 0; it < 8; ++it) {
        const int chunk = it * 256 + tid;
        const int row = chunk >> 4, off = (chunk & 15) * 8;
        const bf16x8 v = *(const bf16x8*)&tile[row * 136 + off];
        *(bf16x8*)(vTout + ((size_t)b * NC + cv0 + row) * NL + lb + off) = v;
      }
      return;
    }

    float cs[4][4], cq[4][4];
    if (STATS) {
#pragma unroll
      for (int i = 0; i < 4; ++i)
#pragma unroll
        for (int j = 0; j < 4; ++j) { cs[i][j] = 0.f; cq[i][j] = 0.f; }
    }

#pragma unroll
    for (int mf = 0; mf < 4; ++mf) {
      const int ocbase = ocb + woc + mf * 16 + lg * 4;
      float4 bv = *(const float4*)&bias[ocbase];
      if (HAS_T) {
        const float4 tv = *(const float4*)&tadd[b * 256 + ocbase];
        bv.x += tv.x; bv.y += tv.y; bv.z += tv.z; bv.w += tv.w;
      }
#pragma unroll
      for (int nf = 0; nf < 4; ++nf) {
        const int l = lb + wl + nf * 16 + l15;
        const f32x4 a = acc[mf][nf];
        float v0 = a[0] + bv.x, v1 = a[1] + bv.y, v2 = a[2] + bv.z, v3 = a[3] + bv.w;
        if (RESM == 1) {
          const float* rp = resf + ((size_t)b * NC + ocbase) * NL + l;
          v0 += rp[0]; v1 += rp[NL]; v2 += rp[2 * (size_t)NL]; v3 += rp[3 * (size_t)NL];
        }
        if (RESM == 2) {
          const ushort4 rv = *(const ushort4*)(resT + ((size_t)b * TROWS + 1 + l) * 256 + ocbase);
          v0 += bf2f(rv.x); v1 += bf2f(rv.y); v2 += bf2f(rv.z); v3 += bf2f(rv.w);
        }
        if (STATS) {
          cs[mf][0] += v0; cq[mf][0] += v0 * v0;
          cs[mf][1] += v1; cq[mf][1] += v1 * v1;
          cs[mf][2] += v2; cq[mf][2] += v2 * v2;
          cs[mf][3] += v3; cq[mf][3] += v3 * v3;
        }
        if (RESM == 2) {
          float* op = outf + ((size_t)b * NC + ocbase) * NL + l;
          op[0] = v0; op[NL] = v1; op[2 * (size_t)NL] = v2; op[3 * (size_t)NL] = v3;
        } else if (OCT == 256) {
          ushort4 st = {f2bf(v0), f2bf(v1), f2bf(v2), f2bf(v3)};
          *(ushort4*)(outT + ((size_t)b * TROWS + 1 + l) * 256 + ocbase) = st;
        } else {
          ushort4 st = {f2bf(v0), f2bf(v1), f2bf(v2), f2bf(v3)};
          *(ushort4*)(outT + ((size_t)b * NL + l) * 512 + ocbase) = st;
        }
      }
    }

    if (STATS) {
      __syncthreads();
      float* sred = (float*)&xs[0][0];
#pragma unroll
      for (int mf = 0; mf < 4; ++mf)
#pragma unroll
        for (int j = 0; j < 4; ++j) {
          float s = cs[mf][j], q = cq[mf][j];
#pragma unroll
          for (int m = 1; m < 16; m <<= 1) { s += __shfl_xor(s, m); q += __shfl_xor(q, m); }
          if (l15 == 0) {
            const int cl = woc + mf * 16 + lg * 4 + j;
            sred[(w & 1) * 128 + cl] = s;
            sred[256 + (w & 1) * 128 + cl] = q;
          }
        }
      __syncthreads();
      if (tid < 128) {
        const float s = sred[tid] + sred[128 + tid];
        const float q = sred[256 + tid] + sred[384 + tid];
        pstatOut[((size_t)b * 16 + lbx) * 256 + ocb + tid] = make_float2(s, q);
      }
    }
  }
}

// ---------------- flash attention: split-KV x2; dual-accumulator QK ----------------
#define AKVB 32
#define ATILES 32

__global__ __launch_bounds__(256, 2)
void attn_mfma(const u16* __restrict__ kq, const u16* __restrict__ vT,
               u16* __restrict__ part, float2* __restrict__ stats)
{
  __shared__ u16 ks[2][32 * 256];
  __shared__ u16 vs[2][256 * 32];

  const int fid = blockIdx.x;
  const int xcd = fid & 7, idx = fid >> 3;
  const int b = (xcd << 1) | (idx & 1);
  const int rest = idx >> 1;
  const int qt = rest & 15, half = rest >> 4;
  const int kvbase = half * 1024;

  const int tid = threadIdx.x;
  const int w = tid >> 6, lane = tid & 63;
  const int l31 = lane & 31, lh = lane >> 5;
  const int q = qt * 128 + w * 32 + l31;

  const u16* kqb = kq + (size_t)b * NL * 512;
  const u16* vb  = vT + (size_t)b * NC * NL;

  auto stage = [&](int buf, int kv0) {
#pragma unroll
    for (int j = 0; j < 4; ++j) {
      const int slot = w * 256 + j * 64 + lane;
      const int r = slot >> 5, c = slot & 31;
      const int g = (c - r) & 31;
      gld16(kqb + (size_t)(kv0 + r) * 512 + g * 8, &ks[buf][(size_t)(w * 256 + j * 64) * 8]);
    }
#pragma unroll
    for (int j = 0; j < 4; ++j) {
      const int slot = w * 256 + j * 64 + lane;
      const int r = slot >> 2, c = slot & 3;
      const int g = (c - r - (r >> 2)) & 3;
      gld16(vb + (size_t)r * NL + kv0 + g * 8, &vs[buf][(size_t)(w * 256 + j * 64) * 8]);
    }
  };

  bf16x8 qf[16];
  {
    const u16* qp = kqb + (size_t)q * 512 + 256 + lh * 8;
#pragma unroll
    for (int kk = 0; kk < 16; ++kk) qf[kk] = *(const bf16x8*)(qp + kk * 16);
  }

  f32x16 o[8];
#pragma unroll
  for (int i = 0; i < 8; ++i)
    o[i] = (f32x16){0.f,0.f,0.f,0.f,0.f,0.f,0.f,0.f,0.f,0.f,0.f,0.f,0.f,0.f,0.f,0.f};
  float m = -1e30f, lsum = 0.f;

  stage(0, kvbase);
  __syncthreads();

  for (int t = 0; t < ATILES; ++t) {
    const int cur = t & 1;
    if (t + 1 < ATILES) stage(cur ^ 1, kvbase + (t + 1) * AKVB);
    const u16* kbase = &ks[cur][0];
    // ---- S = K*Q: two independent 8-deep accumulation chains ----
    f32x16 sa = (f32x16){0.f,0.f,0.f,0.f,0.f,0.f,0.f,0.f,0.f,0.f,0.f,0.f,0.f,0.f,0.f,0.f};
    f32x16 sb = sa;
#pragma unroll
    for (int kk = 0; kk < 16; kk += 2) {
      const int gn0 = 2 * kk + lh;
      const bf16x8 kf0 = *(const bf16x8*)(kbase + (l31 * 32 + ((gn0 + l31) & 31)) * 8);
      sa = __builtin_amdgcn_mfma_f32_32x32x16_bf16(kf0, qf[kk], sa, 0, 0, 0);
      const int gn1 = 2 * (kk + 1) + lh;
      const bf16x8 kf1 = *(const bf16x8*)(kbase + (l31 * 32 + ((gn1 + l31) & 31)) * 8);
      sb = __builtin_amdgcn_mfma_f32_32x32x16_bf16(kf1, qf[kk + 1], sb, 0, 0, 0);
    }
    f32x16 s = sa + sb;
    float tm = s[0];
#pragma unroll
    for (int i = 1; i < 16; ++i) tm = fmaxf(tm, s[i]);
    tm = fmaxf(tm, __shfl_xor(tm, 32));
    if (!__all(tm <= m + DEFER)) {
      const float mn = fmaxf(m, tm);
      const float corr = ex2(m - mn);
      m = mn; lsum *= corr;
#pragma unroll
      for (int i = 0; i < 8; ++i) o[i] *= corr;
    }
    float sum = 0.f;
#pragma unroll
    for (int i = 0; i < 16; ++i) { s[i] = ex2(s[i] - m); sum += s[i]; }
    sum += __shfl_xor(sum, 32);
    lsum += sum;
    u32 pk[8];
#pragma unroll
    for (int i = 0; i < 8; ++i) pk[i] = cvtpk(s[2 * i], s[2 * i + 1]);
    const u16* vbase = &vs[cur][0];
#pragma unroll
    for (int ksx = 0; ksx < 2; ++ksx) {
      const int base = ksx * 4;
      const u32 send0 = lh ? pk[base + 0] : pk[base + 2];
      const u32 send1 = lh ? pk[base + 1] : pk[base + 3];
      const u32 r0 = (u32)__shfl_xor((int)send0, 32);
      const u32 r1 = (u32)__shfl_xor((int)send1, 32);
      union { u32 wd[4]; bf16x8 v; } pu;
      pu.wd[0] = lh ? r0 : pk[base + 0];
      pu.wd[1] = lh ? r1 : pk[base + 1];
      pu.wd[2] = lh ? pk[base + 2] : r0;
      pu.wd[3] = lh ? pk[base + 3] : r1;
      const bf16x8 pf = pu.v;
      const int gn = 2 * ksx + lh;
#pragma unroll
      for (int mf = 0; mf < 8; ++mf) {
        const int row = mf * 32 + l31;
        const bf16x8 vf = *(const bf16x8*)(vbase + (row * 4 + ((gn + row + (row >> 2)) & 3)) * 8);
        o[mf] = __builtin_amdgcn_mfma_f32_32x32x16_bf16(vf, pf, o[mf], 0, 0, 0);
      }
    }
    if (t + 1 < ATILES) __syncthreads();
  }
  u16* pp = part + half * PHALF + ((size_t)b * NL + q) * 256;
#pragma unroll
  for (int mf = 0; mf < 8; ++mf)
#pragma unroll
    for (int rq = 0; rq < 4; ++rq) {
      ushort4 st;
      st.x = f2bf(o[mf][rq * 4 + 0]);
      st.y = f2bf(o[mf][rq * 4 + 1]);
      st.z = f2bf(o[mf][rq * 4 + 2]);
      st.w = f2bf(o[mf][rq * 4 + 3]);
      *(ushort4*)(pp + mf * 32 + 8 * rq + 4 * lh) = st;
    }
  if (lane < 32)
    stats[((size_t)half * NB + b) * NL + q] = make_float2(m, lsum);
}

// ---------------- combine: T-layout partials -> avT bf16 + 16-chunk stats ----------------
__global__ __launch_bounds__(256)
void attn_combine(const u16* __restrict__ part, const float2* __restrict__ stats,
                  u16* __restrict__ avT, float2* __restrict__ pstat)
{
  __shared__ float2 sst[2][128];
  __shared__ float redS[8][256], redQ[8][256];
  const int chunk = blockIdx.x, b = blockIdx.y;
  const int t = threadIdx.x;
  const int rg = t >> 5;
  const int cg = (t & 31) * 8;
  const int l0 = chunk * 128;
  if (t < 128) sst[0][t] = stats[(size_t)b * NL + l0 + t];
  else sst[1][t - 128] = stats[((size_t)NB + b) * NL + l0 + (t - 128)];
  __syncthreads();
  float cs[8], cq[8];
#pragma unroll
  for (int k = 0; k < 8; ++k) { cs[k] = 0.f; cq[k] = 0.f; }
#pragma unroll 4
  for (int j = 0; j < 16; ++j) {
    const int l = j * 8 + rg;
    const float2 sa = sst[0][l], sb = sst[1][l];
    const float M = fmaxf(sa.x, sb.x);
    const float e0 = ex2(sa.x - M), e1 = ex2(sb.x - M);
    const float den = 1.f / (sa.y * e0 + sb.y * e1);
    const size_t off = ((size_t)b * NL + l0 + l) * 256 + cg;
    const bf16x8 a8 = *(const bf16x8*)(part + off);
    const bf16x8 b8 = *(const bf16x8*)(part + PHALF + off);
    u16 o8[8];
#pragma unroll
    for (int k = 0; k < 8; ++k) {
      const float r = (bf2f(((const u16*)&a8)[k]) * e0 + bf2f(((const u16*)&b8)[k]) * e1) * den;
      o8[k] = f2bf(r);
      cs[k] += r; cq[k] += r * r;
    }
    *(bf16x8*)(avT + ((size_t)b * TROWS + 1 + l0 + l) * 256 + cg) = *(bf16x8*)o8;
  }
#pragma unroll
  for (int k = 0; k < 8; ++k) { redS[rg][cg + k] = cs[k]; redQ[rg][cg + k] = cq[k]; }
  __syncthreads();
  {
    float S = 0.f, Q = 0.f;
#pragma unroll
    for (int r = 0; r < 8; ++r) { S += redS[r][t]; Q += redQ[r][t]; }
    pstat[((size_t)b * 16 + chunk) * 256 + t] = make_float2(S, Q);
  }
}

extern "C" void kernel_launch(void* const* d_in, const int* in_sizes, int n_in,
                              void* d_out, int out_size, void* d_ws, size_t ws_size,
                              hipStream_t stream)
{
  (void)in_sizes; (void)n_in; (void)out_size; (void)ws_size;
  const float* x        = (const float*)d_in[0];
  const float* t        = (const float*)d_in[1];
  const float* r1_gn1_w = (const float*)d_in[2];
  const float* r1_gn1_b = (const float*)d_in[3];
  const float* r1_c1_w  = (const float*)d_in[4];
  const float* r1_c1_b  = (const float*)d_in[5];
  const float* r1_gn2_w = (const float*)d_in[6];
  const float* r1_gn2_b = (const float*)d_in[7];
  const float* r1_c2_w  = (const float*)d_in[8];
  const float* r1_c2_b  = (const float*)d_in[9];
  const float* r2_gn1_w = (const float*)d_in[10];
  const float* r2_gn1_b = (const float*)d_in[11];
  const float* r2_c1_w  = (const float*)d_in[12];
  const float* r2_c1_b  = (const float*)d_in[13];
  const float* r2_gn2_w = (const float*)d_in[14];
  const float* r2_gn2_b = (const float*)d_in[15];
  const float* r2_c2_w  = (const float*)d_in[16];
  const float* r2_c2_b  = (const float*)d_in[17];
  const float* lin_w    = (const float*)d_in[18];
  const float* lin_b    = (const float*)d_in[19];

  float* out = (float*)d_out;

  const size_t TSZ = (size_t)NB * TROWS * 256 * 2;           // 16,793,600
  u16* tA  = (u16*)d_ws;
  u16* tB  = (u16*)((char*)d_ws + TSZ);
  u16* kq  = tB;                                             // spans [TSZ, 3TSZ)
  u16* tC  = (u16*)((char*)d_ws + 3 * TSZ);
  u16* vT  = tC;
  u16* Wp  = (u16*)((char*)d_ws + 4 * TSZ);
  u16* Wq  = Wp + 4 * 196608;
  float* bq = (float*)(Wq + 196608);
  float2* pstat = (float2*)((char*)bq + 4096);               // 512 KB
  float2* astat = (float2*)((char*)pstat + 524288);          // 512 KB attn m/lsum

  const dim3 gPack(768, 5);
  const dim3 gC(32, 1, NB);
  const dim3 gQ(64, 1, NB);
  const dim3 gS16(16, NB);
  const dim3 gA64(64, NB);
  const dim3 gCmb(16, NB);

  pack_w<<<gPack, 256, 0, stream>>>(r1_c1_w, r1_c2_w, r2_c1_w, r2_c2_w, lin_w, lin_b, Wp, Wq, bq);

  // res1
  stats_f32<<<NB * NC, 256, 0, stream>>>(x, pstat);
  apply_f32T<<<gA64, 256, 0, stream>>>(x, pstat, r1_gn1_w, r1_gn1_b, tA);
  conv_mfma<256, 3, true, 0, true><<<gC, 256, 0, stream>>>(tA, Wp, r1_c1_b, t, tB, nullptr, nullptr, nullptr, nullptr, pstat);
  apply_TT<<<gS16, 256, 0, stream>>>(tB, pstat, r1_gn2_w, r1_gn2_b, tC);
  conv_mfma<256, 3, false, 1, false><<<gC, 256, 0, stream>>>(tC, Wp + 196608, r1_c2_b, nullptr, tA, nullptr, x, nullptr, nullptr, nullptr);

  // attention
  conv_mfma<768, 1, false, 0, false><<<gQ, 256, 0, stream>>>(tA, Wq, bq, nullptr, kq, vT, nullptr, nullptr, nullptr, nullptr);
  attn_mfma<<<512, 256, 0, stream>>>(kq, vT, (u16*)out, astat);
  attn_combine<<<gCmb, 256, 0, stream>>>((const u16*)out, astat, tA, pstat);

  // res2
  apply_TT<<<gS16, 256, 0, stream>>>(tA, pstat, r2_gn1_w, r2_gn1_b, tC);
  conv_mfma<256, 3, true, 0, true><<<gC, 256, 0, stream>>>(tC, Wp + 2 * 196608, r2_c1_b, t, tB, nullptr, nullptr, nullptr, nullptr, pstat);
  apply_TT<<<gS16, 256, 0, stream>>>(tB, pstat, r2_gn2_w, r2_gn2_b, tC);
  conv_mfma<256, 3, false, 2, false><<<gC, 256, 0, stream>>>(tC, Wp + 3 * 196608, r2_c2_b, nullptr, nullptr, nullptr, nullptr, tA, out, nullptr);
}

// Round 16
// 346.035 us; speedup vs baseline: 1.0526x; 1.0526x over previous
//
#include <hip/hip_runtime.h>

typedef unsigned short u16;
typedef unsigned int u32;
typedef __attribute__((ext_vector_type(8))) short bf16x8;
typedef __attribute__((ext_vector_type(4))) float f32x4;
typedef __attribute__((ext_vector_type(16))) float f32x16;

#define NB 16
#define NC 256
#define NL 2048
#define EPS 1e-5f
#define QSC2 0.0901684401f   // (1/sqrt(256)) * log2(e)
#define DEFER 11.54f         // 8 * log2(e)
#define TROWS 2050
#define PHALF ((size_t)NB * NC * NL)

__device__ __forceinline__ float bf2f(u16 a) {
  union { unsigned u; float f; } v; v.u = (unsigned)a << 16; return v.f;
}
__device__ __forceinline__ u16 f2bf(float f) {
  union { float f; unsigned u; } v; v.f = f;
  return (u16)((v.u + 0x7fffu + ((v.u >> 16) & 1u)) >> 16);
}
__device__ __forceinline__ u32 cvtpk(float lo, float hi) {
  u32 r;
  asm("v_cvt_pk_bf16_f32 %0, %1, %2" : "=v"(r) : "v"(lo), "v"(hi));
  return r;
}
__device__ __forceinline__ float ex2(float x) {
  float r;
  asm("v_exp_f32 %0, %1" : "=v"(r) : "v"(x));
  return r;
}
__device__ __forceinline__ void gld16(const void* gsrc, void* ldst) {
  __builtin_amdgcn_global_load_lds(
      (const __attribute__((address_space(1))) void*)gsrc,
      (__attribute__((address_space(3))) void*)ldst, 16, 0, 0);
}

// ---------------- weight pack ----------------
__global__ __launch_bounds__(256)
void pack_w(const float* __restrict__ w1, const float* __restrict__ w2,
            const float* __restrict__ w3, const float* __restrict__ w4,
            const float* __restrict__ lw, const float* __restrict__ lb,
            u16* __restrict__ Wp, u16* __restrict__ Wq, float* __restrict__ bq)
{
  const int a = blockIdx.y;
  const int gid = blockIdx.x * 256 + threadIdx.x;
  if (a < 4) {
    const float* w = a == 0 ? w1 : a == 1 ? w2 : a == 2 ? w3 : w4;
    const int d = gid >> 16, rem = gid & 65535;
    const int oc = rem >> 8, ic = rem & 255;
    Wp[a * 196608 + gid] = f2bf(w[(oc * 256 + ic) * 3 + d]);
  } else {
    const int oc = gid >> 8;
    const float s = (oc >= 256 && oc < 512) ? QSC2 : 1.0f;
    Wq[gid] = f2bf(lw[gid] * s);
    if (gid < 768) bq[gid] = lb[gid] * ((gid >= 256 && gid < 512) ? QSC2 : 1.0f);
  }
}

// ---------------- GN stats: fp32 (C,L) -> pstat[b*256+c] ----
__global__ __launch_bounds__(256)
void stats_f32(const float* __restrict__ x, float2* __restrict__ pstat)
{
  const int blk = blockIdx.x;
  const float* p = x + (size_t)blk * NL + threadIdx.x * 8;
  const float4 a = ((const float4*)p)[0];
  const float4 c4 = ((const float4*)p)[1];
  float s = (a.x + a.y) + (a.z + a.w) + (c4.x + c4.y) + (c4.z + c4.w);
  float ss = a.x*a.x + a.y*a.y + a.z*a.z + a.w*a.w + c4.x*c4.x + c4.y*c4.y + c4.z*c4.z + c4.w*c4.w;
#pragma unroll
  for (int o = 32; o > 0; o >>= 1) { s += __shfl_down(s, o); ss += __shfl_down(ss, o); }
  __shared__ float2 red[4];
  if ((threadIdx.x & 63) == 0) red[threadIdx.x >> 6] = make_float2(s, ss);
  __syncthreads();
  if (threadIdx.x == 0)
    pstat[blk] = make_float2(red[0].x + red[1].x + red[2].x + red[3].x,
                             red[0].y + red[1].y + red[2].y + red[3].y);
}

// ---------------- GN apply: fp32 (C,L) -> bf16 T padded (bank-aware transpose) ----
__global__ __launch_bounds__(256)
void apply_f32T(const float* __restrict__ x, const float2* __restrict__ pstat,
                const float* __restrict__ gw, const float* __restrict__ gb,
                u16* __restrict__ outT)
{
  __shared__ float2 chs[256];
  __shared__ float gm[32], gi[32];
  __shared__ float ta[32][257];
  const int t = threadIdx.x, b = blockIdx.y;
  const int L0 = blockIdx.x * 32;
  chs[t] = pstat[b * 256 + t];
  __syncthreads();
  if (t < 32) {
    float S = 0.f, SS = 0.f;
#pragma unroll
    for (int j = 0; j < 8; ++j) { S += chs[t * 8 + j].x; SS += chs[t * 8 + j].y; }
    const float mean = S * (1.f / 16384.f);
    const float var = SS * (1.f / 16384.f) - mean * mean;
    gm[t] = mean; gi[t] = rsqrtf(var + EPS);
  }
  {
    const int cR = t >> 3, lq = (t & 7) * 4;
#pragma unroll
    for (int i = 0; i < 8; ++i) {
      const int c = i * 32 + cR;
      const float4 v = *(const float4*)&x[((size_t)b * NC + c) * NL + L0 + lq];
      ta[lq + 0][c] = v.x; ta[lq + 1][c] = v.y; ta[lq + 2][c] = v.z; ta[lq + 3][c] = v.w;
    }
  }
  __syncthreads();
  const int g = t & 31, rbase = t >> 5;
  float ga[8], be[8];
#pragma unroll
  for (int j = 0; j < 4; ++j)
#pragma unroll
    for (int k = 0; k < 2; ++k) {
      const int c = 2 * g + 64 * j + k;
      const int grp = c >> 3;
      ga[j * 2 + k] = gw[c] * gi[grp];
      be[j * 2 + k] = gb[c] - gm[grp] * ga[j * 2 + k];
    }
#pragma unroll
  for (int ri = 0; ri < 4; ++ri) {
    const int row = rbase + ri * 8;
    u16* orow = outT + ((size_t)b * TROWS + 1 + L0 + row) * 256;
#pragma unroll
    for (int j = 0; j < 4; ++j) {
      const int c = 2 * g + 64 * j;
      const float v0 = ta[row][c], v1 = ta[row][c + 1];
      ushort2 o;
      o.x = f2bf(fmaxf(fmaf(v0, ga[j * 2], be[j * 2]), 0.f));
      o.y = f2bf(fmaxf(fmaf(v1, ga[j * 2 + 1], be[j * 2 + 1]), 0.f));
      *(ushort2*)(orow + c) = o;
    }
  }
  if (blockIdx.x == 0 && t < 128) {
    const int r = (t >> 6) ? 2049 : 0;
    *(ushort4*)(outT + ((size_t)b * TROWS + r) * 256 + (t & 63) * 4) = (ushort4){0, 0, 0, 0};
  }
}

// ---------------- GN apply: bf16 T -> bf16 T padded (16-chunk partial stats) ----------------
__global__ __launch_bounds__(256)
void apply_TT(const u16* __restrict__ inT, const float2* __restrict__ pstat,
              const float* __restrict__ gw, const float* __restrict__ gb,
              u16* __restrict__ outT)
{
  __shared__ float2 chs[256];
  __shared__ float gm[32], gi[32];
  const int t = threadIdx.x, b = blockIdx.y;
  {
    float S = 0.f, SS = 0.f;
#pragma unroll
    for (int p = 0; p < 16; ++p) {
      const float2 v = pstat[((size_t)b * 16 + p) * 256 + t];
      S += v.x; SS += v.y;
    }
    chs[t] = make_float2(S, SS);
  }
  __syncthreads();
  if (t < 32) {
    float S = 0.f, SS = 0.f;
#pragma unroll
    for (int j = 0; j < 8; ++j) { S += chs[t * 8 + j].x; SS += chs[t * 8 + j].y; }
    const float mean = S * (1.f / 16384.f);
    const float var = SS * (1.f / 16384.f) - mean * mean;
    gm[t] = mean; gi[t] = rsqrtf(var + EPS);
  }
  __syncthreads();
  const int g = t & 31;
  float ga[8], be[8];
#pragma unroll
  for (int j = 0; j < 8; ++j) {
    ga[j] = gw[g * 8 + j] * gi[g];
    be[j] = gb[g * 8 + j] - gm[g] * ga[j];
  }
#pragma unroll
  for (int j = 0; j < 16; ++j) {
    const int row = blockIdx.x * 128 + j * 8 + (t >> 5);
    const size_t off = ((size_t)b * TROWS + 1 + row) * 256 + g * 8;
    const bf16x8 h = *(const bf16x8*)(inT + off);
    u16 o[8];
#pragma unroll
    for (int i = 0; i < 8; ++i)
      o[i] = f2bf(fmaxf(fmaf(bf2f(((const u16*)&h)[i]), ga[i], be[i]), 0.f));
    *(bf16x8*)(outT + off) = *(bf16x8*)o;
  }
  if (blockIdx.x == 0 && t < 128) {
    const int r = (t >> 6) ? 2049 : 0;
    *(ushort4*)(outT + ((size_t)b * TROWS + r) * 256 + (t & 63) * 4) = (ushort4){0, 0, 0, 0};
  }
}

// ---------------- conv GEMM via MFMA (3-deep W prefetch, r14) ----------------
template<int OCT, int KD, bool HAS_T, int RESM, bool STATS>
__global__ __launch_bounds__(256, 2)
void conv_mfma(const u16* __restrict__ xT, const u16* __restrict__ Wp,
               const float* __restrict__ bias, const float* __restrict__ tadd,
               u16* __restrict__ outT, u16* __restrict__ vTout,
               const float* __restrict__ resf, const u16* __restrict__ resT,
               float* __restrict__ outf, float2* __restrict__ pstatOut)
{
  constexpr int DOFF = (KD == 3) ? 0 : 1;
  __shared__ __align__(16) u16 xs[2][130 * 128];
  const int bx = blockIdx.x;
  const int b = blockIdx.z;
  int lbx, ocb0, nsub;
  if (OCT == 256) {
    const int wid = (bx & 7) * 4 + (bx >> 3);
    lbx = wid >> 1; ocb0 = (wid & 1) * 128; nsub = 1;
  } else {
    const int wid = (bx & 7) * 8 + (bx >> 3);
    const int yy = wid & 3;
    lbx = wid >> 2;
    if (yy < 2) { ocb0 = yy * 256; nsub = 2; }
    else { ocb0 = 512 + (yy - 2) * 128; nsub = 1; }
  }
  const int lb = lbx * 128;
  const int tid = threadIdx.x;
  const int w = tid >> 6, lane = tid & 63;
  const int l15 = lane & 15, lg = lane >> 4;
  const int woc = (w >> 1) * 64, wl = (w & 1) * 64;

  const u16* xTb = xT + ((size_t)b * TROWS + lb) * 256;

  auto stageX = [&](int buf, int ich) {
    u16* xb = &xs[buf][0];
#pragma unroll
    for (int j = 0; j < 8; ++j) {
      const int slot = w * 512 + j * 64 + lane;
      const int row = slot >> 4, g0 = slot & 15;
      const int g = (g0 & 8) | ((g0 ^ row) & 7);
      gld16(xTb + (size_t)row * 256 + ich * 128 + g * 8, xb + (size_t)(w * 512 + j * 64) * 8);
    }
    if (w == 0 && lane < 32) {
      const int slot = 2048 + lane;
      const int row = slot >> 4, g0 = slot & 15;
      const int g = (g0 & 8) | ((g0 ^ row) & 7);
      gld16(xTb + (size_t)row * 256 + ich * 128 + g * 8, xb + (size_t)2048 * 8);
    }
  };
  auto loadW = [&](bf16x8 (&af)[KD][4], int p, int ocb) {
    const int ich = p >> 2, kc = p & 3;
#pragma unroll
    for (int d = 0; d < KD; ++d)
#pragma unroll
      for (int mf = 0; mf < 4; ++mf)
        af[d][mf] = *(const bf16x8*)(Wp + ((size_t)d * OCT + ocb + woc + mf * 16 + l15) * 256
                                        + ich * 128 + kc * 32 + lg * 8);
  };

  stageX(0, 0);
  __syncthreads();
  stageX(1, 1);

  for (int sidx = 0; sidx < nsub; ++sidx) {
    const int ocb = ocb0 + sidx * 128;
    f32x4 acc[4][4];
#pragma unroll
    for (int i = 0; i < 4; ++i)
#pragma unroll
      for (int j = 0; j < 4; ++j) acc[i][j] = (f32x4){0.f, 0.f, 0.f, 0.f};

    bf16x8 afbuf[3][KD][4];           // 3-deep W prefetch
    loadW(afbuf[0], 0, ocb);
    loadW(afbuf[1], 1, ocb);

#pragma unroll
    for (int p = 0; p < 8; ++p) {
      if (p == 4 && sidx == 0) __syncthreads();
      if (p < 6) loadW(afbuf[(p + 2) % 3], p + 2, ocb);
      const int kc = p & 3;
      const int gg = kc * 4 + lg;
      const char* xb = (const char*)&xs[p >> 2][0];
#pragma unroll
      for (int nf = 0; nf < 4; ++nf) {
#pragma unroll
        for (int d = 0; d < KD; ++d) {
          const int r = wl + nf * 16 + l15 + d + DOFF;
          const int gsr = (gg & 8) | ((gg ^ r) & 7);
          const bf16x8 bf = *(const bf16x8*)(xb + r * 256 + gsr * 16);
#pragma unroll
          for (int mf = 0; mf < 4; ++mf)
            acc[mf][nf] = __builtin_amdgcn_mfma_f32_16x16x32_bf16(afbuf[p % 3][d][mf], bf, acc[mf][nf], 0, 0, 0);
        }
      }
    }

    if (OCT == 768 && ocb0 >= 512) {
      __syncthreads();
      u16* tile = (u16*)&xs[0][0];   // [128][136]
#pragma unroll
      for (int mf = 0; mf < 4; ++mf) {
        const int cl = woc + mf * 16 + lg * 4;
        const float4 bv = *(const float4*)&bias[ocb + cl];
#pragma unroll
        for (int nf = 0; nf < 4; ++nf) {
          const int ll = wl + nf * 16 + l15;
          const f32x4 a = acc[mf][nf];
          tile[(cl + 0) * 136 + ll] = f2bf(a[0] + bv.x);
          tile[(cl + 1) * 136 + ll] = f2bf(a[1] + bv.y);
          tile[(cl + 2) * 136 + ll] = f2bf(a[2] + bv.z);
          tile[(cl + 3) * 136 + ll] = f2bf(a[3] + bv.w);
        }
      }
      __syncthreads();
      const int cv0 = ocb - 512;
#pragma unroll
      for (int it = 0; it < 8; ++it) {
        const int chunk = it * 256 + tid;
        const int row = chunk >> 4, off = (chunk & 15) * 8;
        const bf16x8 v = *(const bf16x8*)&tile[row * 136 + off];
        *(bf16x8*)(vTout + ((size_t)b * NC + cv0 + row) * NL + lb + off) = v;
      }
      return;
    }

    float cs[4][4], cq[4][4];
    if (STATS) {
#pragma unroll
      for (int i = 0; i < 4; ++i)
#pragma unroll
        for (int j = 0; j < 4; ++j) { cs[i][j] = 0.f; cq[i][j] = 0.f; }
    }

#pragma unroll
    for (int mf = 0; mf < 4; ++mf) {
      const int ocbase = ocb + woc + mf * 16 + lg * 4;
      float4 bv = *(const float4*)&bias[ocbase];
      if (HAS_T) {
        const float4 tv = *(const float4*)&tadd[b * 256 + ocbase];
        bv.x += tv.x; bv.y += tv.y; bv.z += tv.z; bv.w += tv.w;
      }
#pragma unroll
      for (int nf = 0; nf < 4; ++nf) {
        const int l = lb + wl + nf * 16 + l15;
        const f32x4 a = acc[mf][nf];
        float v0 = a[0] + bv.x, v1 = a[1] + bv.y, v2 = a[2] + bv.z, v3 = a[3] + bv.w;
        if (RESM == 1) {
          const float* rp = resf + ((size_t)b * NC + ocbase) * NL + l;
          v0 += rp[0]; v1 += rp[NL]; v2 += rp[2 * (size_t)NL]; v3 += rp[3 * (size_t)NL];
        }
        if (RESM == 2) {
          const ushort4 rv = *(const ushort4*)(resT + ((size_t)b * TROWS + 1 + l) * 256 + ocbase);
          v0 += bf2f(rv.x); v1 += bf2f(rv.y); v2 += bf2f(rv.z); v3 += bf2f(rv.w);
        }
        if (STATS) {
          cs[mf][0] += v0; cq[mf][0] += v0 * v0;
          cs[mf][1] += v1; cq[mf][1] += v1 * v1;
          cs[mf][2] += v2; cq[mf][2] += v2 * v2;
          cs[mf][3] += v3; cq[mf][3] += v3 * v3;
        }
        if (RESM == 2) {
          float* op = outf + ((size_t)b * NC + ocbase) * NL + l;
          op[0] = v0; op[NL] = v1; op[2 * (size_t)NL] = v2; op[3 * (size_t)NL] = v3;
        } else if (OCT == 256) {
          ushort4 st = {f2bf(v0), f2bf(v1), f2bf(v2), f2bf(v3)};
          *(ushort4*)(outT + ((size_t)b * TROWS + 1 + l) * 256 + ocbase) = st;
        } else {
          ushort4 st = {f2bf(v0), f2bf(v1), f2bf(v2), f2bf(v3)};
          *(ushort4*)(outT + ((size_t)b * NL + l) * 512 + ocbase) = st;
        }
      }
    }

    if (STATS) {
      __syncthreads();
      float* sred = (float*)&xs[0][0];
#pragma unroll
      for (int mf = 0; mf < 4; ++mf)
#pragma unroll
        for (int j = 0; j < 4; ++j) {
          float s = cs[mf][j], q = cq[mf][j];
#pragma unroll
          for (int m = 1; m < 16; m <<= 1) { s += __shfl_xor(s, m); q += __shfl_xor(q, m); }
          if (l15 == 0) {
            const int cl = woc + mf * 16 + lg * 4 + j;
            sred[(w & 1) * 128 + cl] = s;
            sred[256 + (w & 1) * 128 + cl] = q;
          }
        }
      __syncthreads();
      if (tid < 128) {
        const float s = sred[tid] + sred[128 + tid];
        const float q = sred[256 + tid] + sred[384 + tid];
        pstatOut[((size_t)b * 16 + lbx) * 256 + ocb + tid] = make_float2(s, q);
      }
    }
  }
}

// ---------------- flash attention: split-KV x2; single-acc QK (r14) + tree reductions ----
#define AKVB 32
#define ATILES 32

__global__ __launch_bounds__(256, 2)
void attn_mfma(const u16* __restrict__ kq, const u16* __restrict__ vT,
               u16* __restrict__ part, float2* __restrict__ stats)
{
  __shared__ u16 ks[2][32 * 256];
  __shared__ u16 vs[2][256 * 32];

  const int fid = blockIdx.x;
  const int xcd = fid & 7, idx = fid >> 3;
  const int b = (xcd << 1) | (idx & 1);
  const int rest = idx >> 1;
  const int qt = rest & 15, half = rest >> 4;
  const int kvbase = half * 1024;

  const int tid = threadIdx.x;
  const int w = tid >> 6, lane = tid & 63;
  const int l31 = lane & 31, lh = lane >> 5;
  const int q = qt * 128 + w * 32 + l31;

  const u16* kqb = kq + (size_t)b * NL * 512;
  const u16* vb  = vT + (size_t)b * NC * NL;

  auto stage = [&](int buf, int kv0) {
#pragma unroll
    for (int j = 0; j < 4; ++j) {
      const int slot = w * 256 + j * 64 + lane;
      const int r = slot >> 5, c = slot & 31;
      const int g = (c - r) & 31;
      gld16(kqb + (size_t)(kv0 + r) * 512 + g * 8, &ks[buf][(size_t)(w * 256 + j * 64) * 8]);
    }
#pragma unroll
    for (int j = 0; j < 4; ++j) {
      const int slot = w * 256 + j * 64 + lane;
      const int r = slot >> 2, c = slot & 3;
      const int g = (c - r - (r >> 2)) & 3;
      gld16(vb + (size_t)r * NL + kv0 + g * 8, &vs[buf][(size_t)(w * 256 + j * 64) * 8]);
    }
  };

  bf16x8 qf[16];
  {
    const u16* qp = kqb + (size_t)q * 512 + 256 + lh * 8;
#pragma unroll
    for (int kk = 0; kk < 16; ++kk) qf[kk] = *(const bf16x8*)(qp + kk * 16);
  }

  f32x16 o[8];
#pragma unroll
  for (int i = 0; i < 8; ++i)
    o[i] = (f32x16){0.f,0.f,0.f,0.f,0.f,0.f,0.f,0.f,0.f,0.f,0.f,0.f,0.f,0.f,0.f,0.f};
  float m = -1e30f, lsum = 0.f;

  stage(0, kvbase);
  __syncthreads();

  for (int t = 0; t < ATILES; ++t) {
    const int cur = t & 1;
    if (t + 1 < ATILES) stage(cur ^ 1, kvbase + (t + 1) * AKVB);
    const u16* kbase = &ks[cur][0];
    f32x16 s = (f32x16){0.f,0.f,0.f,0.f,0.f,0.f,0.f,0.f,0.f,0.f,0.f,0.f,0.f,0.f,0.f,0.f};
#pragma unroll
    for (int kk = 0; kk < 16; ++kk) {
      const int gn = 2 * kk + lh;
      const bf16x8 kf = *(const bf16x8*)(kbase + (l31 * 32 + ((gn + l31) & 31)) * 8);
      s = __builtin_amdgcn_mfma_f32_32x32x16_bf16(kf, qf[kk], s, 0, 0, 0);
    }
    // ---- tree max (depth 4, v_max3-fusable) ----
    float m0 = fmaxf(fmaxf(s[0], s[1]), fmaxf(s[2], s[3]));
    float m1 = fmaxf(fmaxf(s[4], s[5]), fmaxf(s[6], s[7]));
    float m2 = fmaxf(fmaxf(s[8], s[9]), fmaxf(s[10], s[11]));
    float m3 = fmaxf(fmaxf(s[12], s[13]), fmaxf(s[14], s[15]));
    float tm = fmaxf(fmaxf(m0, m1), fmaxf(m2, m3));
    tm = fmaxf(tm, __shfl_xor(tm, 32));
    if (!__all(tm <= m + DEFER)) {
      const float mn = fmaxf(m, tm);
      const float corr = ex2(m - mn);
      m = mn; lsum *= corr;
#pragma unroll
      for (int i = 0; i < 8; ++i) o[i] *= corr;
    }
    // ---- exp + tree sum ----
#pragma unroll
    for (int i = 0; i < 16; ++i) s[i] = ex2(s[i] - m);
    {
      float t0 = (s[0] + s[1]) + (s[2] + s[3]);
      float t1 = (s[4] + s[5]) + (s[6] + s[7]);
      float t2 = (s[8] + s[9]) + (s[10] + s[11]);
      float t3 = (s[12] + s[13]) + (s[14] + s[15]);
      float sum = (t0 + t1) + (t2 + t3);
      sum += __shfl_xor(sum, 32);
      lsum += sum;
    }
    u32 pk[8];
#pragma unroll
    for (int i = 0; i < 8; ++i) pk[i] = cvtpk(s[2 * i], s[2 * i + 1]);
    const u16* vbase = &vs[cur][0];
#pragma unroll
    for (int ksx = 0; ksx < 2; ++ksx) {
      const int base = ksx * 4;
      const u32 send0 = lh ? pk[base + 0] : pk[base + 2];
      const u32 send1 = lh ? pk[base + 1] : pk[base + 3];
      const u32 r0 = (u32)__shfl_xor((int)send0, 32);
      const u32 r1 = (u32)__shfl_xor((int)send1, 32);
      union { u32 wd[4]; bf16x8 v; } pu;
      pu.wd[0] = lh ? r0 : pk[base + 0];
      pu.wd[1] = lh ? r1 : pk[base + 1];
      pu.wd[2] = lh ? pk[base + 2] : r0;
      pu.wd[3] = lh ? pk[base + 3] : r1;
      const bf16x8 pf = pu.v;
      const int gn = 2 * ksx + lh;
#pragma unroll
      for (int mf = 0; mf < 8; ++mf) {
        const int row = mf * 32 + l31;
        const bf16x8 vf = *(const bf16x8*)(vbase + (row * 4 + ((gn + row + (row >> 2)) & 3)) * 8);
        o[mf] = __builtin_amdgcn_mfma_f32_32x32x16_bf16(vf, pf, o[mf], 0, 0, 0);
      }
    }
    if (t + 1 < ATILES) __syncthreads();
  }
  u16* pp = part + half * PHALF + ((size_t)b * NL + q) * 256;
#pragma unroll
  for (int mf = 0; mf < 8; ++mf)
#pragma unroll
    for (int rq = 0; rq < 4; ++rq) {
      ushort4 st;
      st.x = f2bf(o[mf][rq * 4 + 0]);
      st.y = f2bf(o[mf][rq * 4 + 1]);
      st.z = f2bf(o[mf][rq * 4 + 2]);
      st.w = f2bf(o[mf][rq * 4 + 3]);
      *(ushort4*)(pp + mf * 32 + 8 * rq + 4 * lh) = st;
    }
  if (lane < 32)
    stats[((size_t)half * NB + b) * NL + q] = make_float2(m, lsum);
}

// ---------------- combine: T-layout partials -> avT bf16 + 16-chunk stats ----------------
__global__ __launch_bounds__(256)
void attn_combine(const u16* __restrict__ part, const float2* __restrict__ stats,
                  u16* __restrict__ avT, float2* __restrict__ pstat)
{
  __shared__ float2 sst[2][128];
  __shared__ float redS[8][256], redQ[8][256];
  const int chunk = blockIdx.x, b = blockIdx.y;
  const int t = threadIdx.x;
  const int rg = t >> 5;
  const int cg = (t & 31) * 8;
  const int l0 = chunk * 128;
  if (t < 128) sst[0][t] = stats[(size_t)b * NL + l0 + t];
  else sst[1][t - 128] = stats[((size_t)NB + b) * NL + l0 + (t - 128)];
  __syncthreads();
  float cs[8], cq[8];
#pragma unroll
  for (int k = 0; k < 8; ++k) { cs[k] = 0.f; cq[k] = 0.f; }
#pragma unroll 4
  for (int j = 0; j < 16; ++j) {
    const int l = j * 8 + rg;
    const float2 sa = sst[0][l], sb = sst[1][l];
    const float M = fmaxf(sa.x, sb.x);
    const float e0 = ex2(sa.x - M), e1 = ex2(sb.x - M);
    const float den = 1.f / (sa.y * e0 + sb.y * e1);
    const size_t off = ((size_t)b * NL + l0 + l) * 256 + cg;
    const bf16x8 a8 = *(const bf16x8*)(part + off);
    const bf16x8 b8 = *(const bf16x8*)(part + PHALF + off);
    u16 o8[8];
#pragma unroll
    for (int k = 0; k < 8; ++k) {
      const float r = (bf2f(((const u16*)&a8)[k]) * e0 + bf2f(((const u16*)&b8)[k]) * e1) * den;
      o8[k] = f2bf(r);
      cs[k] += r; cq[k] += r * r;
    }
    *(bf16x8*)(avT + ((size_t)b * TROWS + 1 + l0 + l) * 256 + cg) = *(bf16x8*)o8;
  }
#pragma unroll
  for (int k = 0; k < 8; ++k) { redS[rg][cg + k] = cs[k]; redQ[rg][cg + k] = cq[k]; }
  __syncthreads();
  {
    float S = 0.f, Q = 0.f;
#pragma unroll
    for (int r = 0; r < 8; ++r) { S += redS[r][t]; Q += redQ[r][t]; }
    pstat[((size_t)b * 16 + chunk) * 256 + t] = make_float2(S, Q);
  }
}

extern "C" void kernel_launch(void* const* d_in, const int* in_sizes, int n_in,
                              void* d_out, int out_size, void* d_ws, size_t ws_size,
                              hipStream_t stream)
{
  (void)in_sizes; (void)n_in; (void)out_size; (void)ws_size;
  const float* x        = (const float*)d_in[0];
  const float* t        = (const float*)d_in[1];
  const float* r1_gn1_w = (const float*)d_in[2];
  const float* r1_gn1_b = (const float*)d_in[3];
  const float* r1_c1_w  = (const float*)d_in[4];
  const float* r1_c1_b  = (const float*)d_in[5];
  const float* r1_gn2_w = (const float*)d_in[6];
  const float* r1_gn2_b = (const float*)d_in[7];
  const float* r1_c2_w  = (const float*)d_in[8];
  const float* r1_c2_b  = (const float*)d_in[9];
  const float* r2_gn1_w = (const float*)d_in[10];
  const float* r2_gn1_b = (const float*)d_in[11];
  const float* r2_c1_w  = (const float*)d_in[12];
  const float* r2_c1_b  = (const float*)d_in[13];
  const float* r2_gn2_w = (const float*)d_in[14];
  const float* r2_gn2_b = (const float*)d_in[15];
  const float* r2_c2_w  = (const float*)d_in[16];
  const float* r2_c2_b  = (const float*)d_in[17];
  const float* lin_w    = (const float*)d_in[18];
  const float* lin_b    = (const float*)d_in[19];

  float* out = (float*)d_out;

  const size_t TSZ = (size_t)NB * TROWS * 256 * 2;           // 16,793,600
  u16* tA  = (u16*)d_ws;
  u16* tB  = (u16*)((char*)d_ws + TSZ);
  u16* kq  = tB;                                             // spans [TSZ, 3TSZ)
  u16* tC  = (u16*)((char*)d_ws + 3 * TSZ);
  u16* vT  = tC;
  u16* Wp  = (u16*)((char*)d_ws + 4 * TSZ);
  u16* Wq  = Wp + 4 * 196608;
  float* bq = (float*)(Wq + 196608);
  float2* pstat = (float2*)((char*)bq + 4096);               // 512 KB
  float2* astat = (float2*)((char*)pstat + 524288);          // 512 KB attn m/lsum

  const dim3 gPack(768, 5);
  const dim3 gC(32, 1, NB);
  const dim3 gQ(64, 1, NB);
  const dim3 gS16(16, NB);
  const dim3 gA64(64, NB);
  const dim3 gCmb(16, NB);

  pack_w<<<gPack, 256, 0, stream>>>(r1_c1_w, r1_c2_w, r2_c1_w, r2_c2_w, lin_w, lin_b, Wp, Wq, bq);

  // res1
  stats_f32<<<NB * NC, 256, 0, stream>>>(x, pstat);
  apply_f32T<<<gA64, 256, 0, stream>>>(x, pstat, r1_gn1_w, r1_gn1_b, tA);
  conv_mfma<256, 3, true, 0, true><<<gC, 256, 0, stream>>>(tA, Wp, r1_c1_b, t, tB, nullptr, nullptr, nullptr, nullptr, pstat);
  apply_TT<<<gS16, 256, 0, stream>>>(tB, pstat, r1_gn2_w, r1_gn2_b, tC);
  conv_mfma<256, 3, false, 1, false><<<gC, 256, 0, stream>>>(tC, Wp + 196608, r1_c2_b, nullptr, tA, nullptr, x, nullptr, nullptr, nullptr);

  // attention
  conv_mfma<768, 1, false, 0, false><<<gQ, 256, 0, stream>>>(tA, Wq, bq, nullptr, kq, vT, nullptr, nullptr, nullptr, nullptr);
  attn_mfma<<<512, 256, 0, stream>>>(kq, vT, (u16*)out, astat);
  attn_combine<<<gCmb, 256, 0, stream>>>((const u16*)out, astat, tA, pstat);

  // res2
  apply_TT<<<gS16, 256, 0, stream>>>(tA, pstat, r2_gn1_w, r2_gn1_b, tC);
  conv_mfma<256, 3, true, 0, true><<<gC, 256, 0, stream>>>(tC, Wp + 2 * 196608, r2_c1_b, t, tB, nullptr, nullptr, nullptr, nullptr, pstat);
  apply_TT<<<gS16, 256, 0, stream>>>(tB, pstat, r2_gn2_w, r2_gn2_b, tC);
  conv_mfma<256, 3, false, 2, false><<<gC, 256, 0, stream>>>(tC, Wp + 3 * 196608, r2_c2_b, nullptr, nullptr, nullptr, nullptr, tA, out, nullptr);
}

// Round 17
// 339.820 us; speedup vs baseline: 1.0718x; 1.0183x over previous
//
#include <hip/hip_runtime.h>

typedef unsigned short u16;
typedef unsigned int u32;
typedef __attribute__((ext_vector_type(8))) short bf16x8;
typedef __attribute__((ext_vector_type(4))) float f32x4;
typedef __attribute__((ext_vector_type(16))) float f32x16;

#define NB 16
#define NC 256
#define NL 2048
#define EPS 1e-5f
#define QSC2 0.0901684401f   // (1/sqrt(256)) * log2(e)
#define DEFER 11.54f         // 8 * log2(e)
#define TROWS 2050
#define PHALF ((size_t)NB * NC * NL)

__device__ __forceinline__ float bf2f(u16 a) {
  union { unsigned u; float f; } v; v.u = (unsigned)a << 16; return v.f;
}
__device__ __forceinline__ u16 f2bf(float f) {
  union { float f; unsigned u; } v; v.f = f;
  return (u16)((v.u + 0x7fffu + ((v.u >> 16) & 1u)) >> 16);
}
__device__ __forceinline__ u32 cvtpk(float lo, float hi) {
  u32 r;
  asm("v_cvt_pk_bf16_f32 %0, %1, %2" : "=v"(r) : "v"(lo), "v"(hi));
  return r;
}
__device__ __forceinline__ float ex2(float x) {
  float r;
  asm("v_exp_f32 %0, %1" : "=v"(r) : "v"(x));
  return r;
}
__device__ __forceinline__ void gld16(const void* gsrc, void* ldst) {
  __builtin_amdgcn_global_load_lds(
      (const __attribute__((address_space(1))) void*)gsrc,
      (__attribute__((address_space(3))) void*)ldst, 16, 0, 0);
}

// ---------------- weight pack ----------------
__global__ __launch_bounds__(256)
void pack_w(const float* __restrict__ w1, const float* __restrict__ w2,
            const float* __restrict__ w3, const float* __restrict__ w4,
            const float* __restrict__ lw, const float* __restrict__ lb,
            u16* __restrict__ Wp, u16* __restrict__ Wq, float* __restrict__ bq)
{
  const int a = blockIdx.y;
  const int gid = blockIdx.x * 256 + threadIdx.x;
  if (a < 4) {
    const float* w = a == 0 ? w1 : a == 1 ? w2 : a == 2 ? w3 : w4;
    const int d = gid >> 16, rem = gid & 65535;
    const int oc = rem >> 8, ic = rem & 255;
    Wp[a * 196608 + gid] = f2bf(w[(oc * 256 + ic) * 3 + d]);
  } else {
    const int oc = gid >> 8;
    const float s = (oc >= 256 && oc < 512) ? QSC2 : 1.0f;
    Wq[gid] = f2bf(lw[gid] * s);
    if (gid < 768) bq[gid] = lb[gid] * ((gid >= 256 && gid < 512) ? QSC2 : 1.0f);
  }
}

// ---------------- GN stats: fp32 (C,L) -> pstat[b*256+c] ----
__global__ __launch_bounds__(256)
void stats_f32(const float* __restrict__ x, float2* __restrict__ pstat)
{
  const int blk = blockIdx.x;
  const float* p = x + (size_t)blk * NL + threadIdx.x * 8;
  const float4 a = ((const float4*)p)[0];
  const float4 c4 = ((const float4*)p)[1];
  float s = (a.x + a.y) + (a.z + a.w) + (c4.x + c4.y) + (c4.z + c4.w);
  float ss = a.x*a.x + a.y*a.y + a.z*a.z + a.w*a.w + c4.x*c4.x + c4.y*c4.y + c4.z*c4.z + c4.w*c4.w;
#pragma unroll
  for (int o = 32; o > 0; o >>= 1) { s += __shfl_down(s, o); ss += __shfl_down(ss, o); }
  __shared__ float2 red[4];
  if ((threadIdx.x & 63) == 0) red[threadIdx.x >> 6] = make_float2(s, ss);
  __syncthreads();
  if (threadIdx.x == 0)
    pstat[blk] = make_float2(red[0].x + red[1].x + red[2].x + red[3].x,
                             red[0].y + red[1].y + red[2].y + red[3].y);
}

// ---------------- GN apply: fp32 (C,L) -> bf16 T padded (bank-aware transpose) ----
__global__ __launch_bounds__(256)
void apply_f32T(const float* __restrict__ x, const float2* __restrict__ pstat,
                const float* __restrict__ gw, const float* __restrict__ gb,
                u16* __restrict__ outT)
{
  __shared__ float2 chs[256];
  __shared__ float gm[32], gi[32];
  __shared__ float ta[32][257];
  const int t = threadIdx.x, b = blockIdx.y;
  const int L0 = blockIdx.x * 32;
  chs[t] = pstat[b * 256 + t];
  __syncthreads();
  if (t < 32) {
    float S = 0.f, SS = 0.f;
#pragma unroll
    for (int j = 0; j < 8; ++j) { S += chs[t * 8 + j].x; SS += chs[t * 8 + j].y; }
    const float mean = S * (1.f / 16384.f);
    const float var = SS * (1.f / 16384.f) - mean * mean;
    gm[t] = mean; gi[t] = rsqrtf(var + EPS);
  }
  {
    const int cR = t >> 3, lq = (t & 7) * 4;
#pragma unroll
    for (int i = 0; i < 8; ++i) {
      const int c = i * 32 + cR;
      const float4 v = *(const float4*)&x[((size_t)b * NC + c) * NL + L0 + lq];
      ta[lq + 0][c] = v.x; ta[lq + 1][c] = v.y; ta[lq + 2][c] = v.z; ta[lq + 3][c] = v.w;
    }
  }
  __syncthreads();
  const int g = t & 31, rbase = t >> 5;
  float ga[8], be[8];
#pragma unroll
  for (int j = 0; j < 4; ++j)
#pragma unroll
    for (int k = 0; k < 2; ++k) {
      const int c = 2 * g + 64 * j + k;
      const int grp = c >> 3;
      ga[j * 2 + k] = gw[c] * gi[grp];
      be[j * 2 + k] = gb[c] - gm[grp] * ga[j * 2 + k];
    }
#pragma unroll
  for (int ri = 0; ri < 4; ++ri) {
    const int row = rbase + ri * 8;
    u16* orow = outT + ((size_t)b * TROWS + 1 + L0 + row) * 256;
#pragma unroll
    for (int j = 0; j < 4; ++j) {
      const int c = 2 * g + 64 * j;
      const float v0 = ta[row][c], v1 = ta[row][c + 1];
      ushort2 o;
      o.x = f2bf(fmaxf(fmaf(v0, ga[j * 2], be[j * 2]), 0.f));
      o.y = f2bf(fmaxf(fmaf(v1, ga[j * 2 + 1], be[j * 2 + 1]), 0.f));
      *(ushort2*)(orow + c) = o;
    }
  }
  if (blockIdx.x == 0 && t < 128) {
    const int r = (t >> 6) ? 2049 : 0;
    *(ushort4*)(outT + ((size_t)b * TROWS + r) * 256 + (t & 63) * 4) = (ushort4){0, 0, 0, 0};
  }
}

// ---------------- GN apply: bf16 T -> bf16 T padded (16-chunk partial stats) ----------------
__global__ __launch_bounds__(256)
void apply_TT(const u16* __restrict__ inT, const float2* __restrict__ pstat,
              const float* __restrict__ gw, const float* __restrict__ gb,
              u16* __restrict__ outT)
{
  __shared__ float2 chs[256];
  __shared__ float gm[32], gi[32];
  const int t = threadIdx.x, b = blockIdx.y;
  {
    float S = 0.f, SS = 0.f;
#pragma unroll
    for (int p = 0; p < 16; ++p) {
      const float2 v = pstat[((size_t)b * 16 + p) * 256 + t];
      S += v.x; SS += v.y;
    }
    chs[t] = make_float2(S, SS);
  }
  __syncthreads();
  if (t < 32) {
    float S = 0.f, SS = 0.f;
#pragma unroll
    for (int j = 0; j < 8; ++j) { S += chs[t * 8 + j].x; SS += chs[t * 8 + j].y; }
    const float mean = S * (1.f / 16384.f);
    const float var = SS * (1.f / 16384.f) - mean * mean;
    gm[t] = mean; gi[t] = rsqrtf(var + EPS);
  }
  __syncthreads();
  const int g = t & 31;
  float ga[8], be[8];
#pragma unroll
  for (int j = 0; j < 8; ++j) {
    ga[j] = gw[g * 8 + j] * gi[g];
    be[j] = gb[g * 8 + j] - gm[g] * ga[j];
  }
#pragma unroll
  for (int j = 0; j < 16; ++j) {
    const int row = blockIdx.x * 128 + j * 8 + (t >> 5);
    const size_t off = ((size_t)b * TROWS + 1 + row) * 256 + g * 8;
    const bf16x8 h = *(const bf16x8*)(inT + off);
    u16 o[8];
#pragma unroll
    for (int i = 0; i < 8; ++i)
      o[i] = f2bf(fmaxf(fmaf(bf2f(((const u16*)&h)[i]), ga[i], be[i]), 0.f));
    *(bf16x8*)(outT + off) = *(bf16x8*)o;
  }
  if (blockIdx.x == 0 && t < 128) {
    const int r = (t >> 6) ? 2049 : 0;
    *(ushort4*)(outT + ((size_t)b * TROWS + r) * 256 + (t & 63) * 4) = (ushort4){0, 0, 0, 0};
  }
}

// ---------------- conv GEMM via MFMA (3-deep W prefetch, r14) ----------------
template<int OCT, int KD, bool HAS_T, int RESM, bool STATS>
__global__ __launch_bounds__(256, 2)
void conv_mfma(const u16* __restrict__ xT, const u16* __restrict__ Wp,
               const float* __restrict__ bias, const float* __restrict__ tadd,
               u16* __restrict__ outT, u16* __restrict__ vTout,
               const float* __restrict__ resf, const u16* __restrict__ resT,
               float* __restrict__ outf, float2* __restrict__ pstatOut)
{
  constexpr int DOFF = (KD == 3) ? 0 : 1;
  __shared__ __align__(16) u16 xs[2][130 * 128];
  const int bx = blockIdx.x;
  const int b = blockIdx.z;
  int lbx, ocb0, nsub;
  if (OCT == 256) {
    const int wid = (bx & 7) * 4 + (bx >> 3);
    lbx = wid >> 1; ocb0 = (wid & 1) * 128; nsub = 1;
  } else {
    const int wid = (bx & 7) * 8 + (bx >> 3);
    const int yy = wid & 3;
    lbx = wid >> 2;
    if (yy < 2) { ocb0 = yy * 256; nsub = 2; }
    else { ocb0 = 512 + (yy - 2) * 128; nsub = 1; }
  }
  const int lb = lbx * 128;
  const int tid = threadIdx.x;
  const int w = tid >> 6, lane = tid & 63;
  const int l15 = lane & 15, lg = lane >> 4;
  const int woc = (w >> 1) * 64, wl = (w & 1) * 64;

  const u16* xTb = xT + ((size_t)b * TROWS + lb) * 256;

  auto stageX = [&](int buf, int ich) {
    u16* xb = &xs[buf][0];
#pragma unroll
    for (int j = 0; j < 8; ++j) {
      const int slot = w * 512 + j * 64 + lane;
      const int row = slot >> 4, g0 = slot & 15;
      const int g = (g0 & 8) | ((g0 ^ row) & 7);
      gld16(xTb + (size_t)row * 256 + ich * 128 + g * 8, xb + (size_t)(w * 512 + j * 64) * 8);
    }
    if (w == 0 && lane < 32) {
      const int slot = 2048 + lane;
      const int row = slot >> 4, g0 = slot & 15;
      const int g = (g0 & 8) | ((g0 ^ row) & 7);
      gld16(xTb + (size_t)row * 256 + ich * 128 + g * 8, xb + (size_t)2048 * 8);
    }
  };
  auto loadW = [&](bf16x8 (&af)[KD][4], int p, int ocb) {
    const int ich = p >> 2, kc = p & 3;
#pragma unroll
    for (int d = 0; d < KD; ++d)
#pragma unroll
      for (int mf = 0; mf < 4; ++mf)
        af[d][mf] = *(const bf16x8*)(Wp + ((size_t)d * OCT + ocb + woc + mf * 16 + l15) * 256
                                        + ich * 128 + kc * 32 + lg * 8);
  };

  stageX(0, 0);
  __syncthreads();
  stageX(1, 1);

  for (int sidx = 0; sidx < nsub; ++sidx) {
    const int ocb = ocb0 + sidx * 128;
    f32x4 acc[4][4];
#pragma unroll
    for (int i = 0; i < 4; ++i)
#pragma unroll
      for (int j = 0; j < 4; ++j) acc[i][j] = (f32x4){0.f, 0.f, 0.f, 0.f};

    bf16x8 afbuf[3][KD][4];           // 3-deep W prefetch
    loadW(afbuf[0], 0, ocb);
    loadW(afbuf[1], 1, ocb);

#pragma unroll
    for (int p = 0; p < 8; ++p) {
      if (p == 4 && sidx == 0) __syncthreads();
      if (p < 6) loadW(afbuf[(p + 2) % 3], p + 2, ocb);
      const int kc = p & 3;
      const int gg = kc * 4 + lg;
      const char* xb = (const char*)&xs[p >> 2][0];
#pragma unroll
      for (int nf = 0; nf < 4; ++nf) {
#pragma unroll
        for (int d = 0; d < KD; ++d) {
          const int r = wl + nf * 16 + l15 + d + DOFF;
          const int gsr = (gg & 8) | ((gg ^ r) & 7);
          const bf16x8 bf = *(const bf16x8*)(xb + r * 256 + gsr * 16);
#pragma unroll
          for (int mf = 0; mf < 4; ++mf)
            acc[mf][nf] = __builtin_amdgcn_mfma_f32_16x16x32_bf16(afbuf[p % 3][d][mf], bf, acc[mf][nf], 0, 0, 0);
        }
      }
    }

    if (OCT == 768 && ocb0 >= 512) {
      __syncthreads();
      u16* tile = (u16*)&xs[0][0];   // [128][136]
#pragma unroll
      for (int mf = 0; mf < 4; ++mf) {
        const int cl = woc + mf * 16 + lg * 4;
        const float4 bv = *(const float4*)&bias[ocb + cl];
#pragma unroll
        for (int nf = 0; nf < 4; ++nf) {
          const int ll = wl + nf * 16 + l15;
          const f32x4 a = acc[mf][nf];
          tile[(cl + 0) * 136 + ll] = f2bf(a[0] + bv.x);
          tile[(cl + 1) * 136 + ll] = f2bf(a[1] + bv.y);
          tile[(cl + 2) * 136 + ll] = f2bf(a[2] + bv.z);
          tile[(cl + 3) * 136 + ll] = f2bf(a[3] + bv.w);
        }
      }
      __syncthreads();
      const int cv0 = ocb - 512;
#pragma unroll
      for (int it = 0; it < 8; ++it) {
        const int chunk = it * 256 + tid;
        const int row = chunk >> 4, off = (chunk & 15) * 8;
        const bf16x8 v = *(const bf16x8*)&tile[row * 136 + off];
        *(bf16x8*)(vTout + ((size_t)b * NC + cv0 + row) * NL + lb + off) = v;
      }
      return;
    }

    float cs[4][4], cq[4][4];
    if (STATS) {
#pragma unroll
      for (int i = 0; i < 4; ++i)
#pragma unroll
        for (int j = 0; j < 4; ++j) { cs[i][j] = 0.f; cq[i][j] = 0.f; }
    }

#pragma unroll
    for (int mf = 0; mf < 4; ++mf) {
      const int ocbase = ocb + woc + mf * 16 + lg * 4;
      float4 bv = *(const float4*)&bias[ocbase];
      if (HAS_T) {
        const float4 tv = *(const float4*)&tadd[b * 256 + ocbase];
        bv.x += tv.x; bv.y += tv.y; bv.z += tv.z; bv.w += tv.w;
      }
#pragma unroll
      for (int nf = 0; nf < 4; ++nf) {
        const int l = lb + wl + nf * 16 + l15;
        const f32x4 a = acc[mf][nf];
        float v0 = a[0] + bv.x, v1 = a[1] + bv.y, v2 = a[2] + bv.z, v3 = a[3] + bv.w;
        if (RESM == 1) {
          const float* rp = resf + ((size_t)b * NC + ocbase) * NL + l;
          v0 += rp[0]; v1 += rp[NL]; v2 += rp[2 * (size_t)NL]; v3 += rp[3 * (size_t)NL];
        }
        if (RESM == 2) {
          const ushort4 rv = *(const ushort4*)(resT + ((size_t)b * TROWS + 1 + l) * 256 + ocbase);
          v0 += bf2f(rv.x); v1 += bf2f(rv.y); v2 += bf2f(rv.z); v3 += bf2f(rv.w);
        }
        if (STATS) {
          cs[mf][0] += v0; cq[mf][0] += v0 * v0;
          cs[mf][1] += v1; cq[mf][1] += v1 * v1;
          cs[mf][2] += v2; cq[mf][2] += v2 * v2;
          cs[mf][3] += v3; cq[mf][3] += v3 * v3;
        }
        if (RESM == 2) {
          float* op = outf + ((size_t)b * NC + ocbase) * NL + l;
          op[0] = v0; op[NL] = v1; op[2 * (size_t)NL] = v2; op[3 * (size_t)NL] = v3;
        } else if (OCT == 256) {
          ushort4 st = {f2bf(v0), f2bf(v1), f2bf(v2), f2bf(v3)};
          *(ushort4*)(outT + ((size_t)b * TROWS + 1 + l) * 256 + ocbase) = st;
        } else {
          ushort4 st = {f2bf(v0), f2bf(v1), f2bf(v2), f2bf(v3)};
          *(ushort4*)(outT + ((size_t)b * NL + l) * 512 + ocbase) = st;
        }
      }
    }

    if (STATS) {
      __syncthreads();
      float* sred = (float*)&xs[0][0];
#pragma unroll
      for (int mf = 0; mf < 4; ++mf)
#pragma unroll
        for (int j = 0; j < 4; ++j) {
          float s = cs[mf][j], q = cq[mf][j];
#pragma unroll
          for (int m = 1; m < 16; m <<= 1) { s += __shfl_xor(s, m); q += __shfl_xor(q, m); }
          if (l15 == 0) {
            const int cl = woc + mf * 16 + lg * 4 + j;
            sred[(w & 1) * 128 + cl] = s;
            sred[256 + (w & 1) * 128 + cl] = q;
          }
        }
      __syncthreads();
      if (tid < 128) {
        const float s = sred[tid] + sred[128 + tid];
        const float q = sred[256 + tid] + sred[384 + tid];
        pstatOut[((size_t)b * 16 + lbx) * 256 + ocb + tid] = make_float2(s, q);
      }
    }
  }
}

// ---------------- flash attention: split-KV x2; T-layout partials (r14 exact) ----------------
#define AKVB 32
#define ATILES 32

__global__ __launch_bounds__(256, 2)
void attn_mfma(const u16* __restrict__ kq, const u16* __restrict__ vT,
               u16* __restrict__ part, float2* __restrict__ stats)
{
  __shared__ u16 ks[2][32 * 256];
  __shared__ u16 vs[2][256 * 32];

  const int fid = blockIdx.x;
  const int xcd = fid & 7, idx = fid >> 3;
  const int b = (xcd << 1) | (idx & 1);
  const int rest = idx >> 1;
  const int qt = rest & 15, half = rest >> 4;
  const int kvbase = half * 1024;

  const int tid = threadIdx.x;
  const int w = tid >> 6, lane = tid & 63;
  const int l31 = lane & 31, lh = lane >> 5;
  const int q = qt * 128 + w * 32 + l31;

  const u16* kqb = kq + (size_t)b * NL * 512;
  const u16* vb  = vT + (size_t)b * NC * NL;

  auto stage = [&](int buf, int kv0) {
#pragma unroll
    for (int j = 0; j < 4; ++j) {
      const int slot = w * 256 + j * 64 + lane;
      const int r = slot >> 5, c = slot & 31;
      const int g = (c - r) & 31;
      gld16(kqb + (size_t)(kv0 + r) * 512 + g * 8, &ks[buf][(size_t)(w * 256 + j * 64) * 8]);
    }
#pragma unroll
    for (int j = 0; j < 4; ++j) {
      const int slot = w * 256 + j * 64 + lane;
      const int r = slot >> 2, c = slot & 3;
      const int g = (c - r - (r >> 2)) & 3;
      gld16(vb + (size_t)r * NL + kv0 + g * 8, &vs[buf][(size_t)(w * 256 + j * 64) * 8]);
    }
  };

  bf16x8 qf[16];
  {
    const u16* qp = kqb + (size_t)q * 512 + 256 + lh * 8;
#pragma unroll
    for (int kk = 0; kk < 16; ++kk) qf[kk] = *(const bf16x8*)(qp + kk * 16);
  }

  f32x16 o[8];
#pragma unroll
  for (int i = 0; i < 8; ++i)
    o[i] = (f32x16){0.f,0.f,0.f,0.f,0.f,0.f,0.f,0.f,0.f,0.f,0.f,0.f,0.f,0.f,0.f,0.f};
  float m = -1e30f, lsum = 0.f;

  stage(0, kvbase);
  __syncthreads();

  for (int t = 0; t < ATILES; ++t) {
    const int cur = t & 1;
    if (t + 1 < ATILES) stage(cur ^ 1, kvbase + (t + 1) * AKVB);
    const u16* kbase = &ks[cur][0];
    f32x16 s = (f32x16){0.f,0.f,0.f,0.f,0.f,0.f,0.f,0.f,0.f,0.f,0.f,0.f,0.f,0.f,0.f,0.f};
#pragma unroll
    for (int kk = 0; kk < 16; ++kk) {
      const int gn = 2 * kk + lh;
      const bf16x8 kf = *(const bf16x8*)(kbase + (l31 * 32 + ((gn + l31) & 31)) * 8);
      s = __builtin_amdgcn_mfma_f32_32x32x16_bf16(kf, qf[kk], s, 0, 0, 0);
    }
    float tm = s[0];
#pragma unroll
    for (int i = 1; i < 16; ++i) tm = fmaxf(tm, s[i]);
    tm = fmaxf(tm, __shfl_xor(tm, 32));
    if (!__all(tm <= m + DEFER)) {
      const float mn = fmaxf(m, tm);
      const float corr = ex2(m - mn);
      m = mn; lsum *= corr;
#pragma unroll
      for (int i = 0; i < 8; ++i) o[i] *= corr;
    }
    float sum = 0.f;
#pragma unroll
    for (int i = 0; i < 16; ++i) { s[i] = ex2(s[i] - m); sum += s[i]; }
    sum += __shfl_xor(sum, 32);
    lsum += sum;
    u32 pk[8];
#pragma unroll
    for (int i = 0; i < 8; ++i) pk[i] = cvtpk(s[2 * i], s[2 * i + 1]);
    const u16* vbase = &vs[cur][0];
#pragma unroll
    for (int ksx = 0; ksx < 2; ++ksx) {
      const int base = ksx * 4;
      const u32 send0 = lh ? pk[base + 0] : pk[base + 2];
      const u32 send1 = lh ? pk[base + 1] : pk[base + 3];
      const u32 r0 = (u32)__shfl_xor((int)send0, 32);
      const u32 r1 = (u32)__shfl_xor((int)send1, 32);
      union { u32 wd[4]; bf16x8 v; } pu;
      pu.wd[0] = lh ? r0 : pk[base + 0];
      pu.wd[1] = lh ? r1 : pk[base + 1];
      pu.wd[2] = lh ? pk[base + 2] : r0;
      pu.wd[3] = lh ? pk[base + 3] : r1;
      const bf16x8 pf = pu.v;
      const int gn = 2 * ksx + lh;
#pragma unroll
      for (int mf = 0; mf < 8; ++mf) {
        const int row = mf * 32 + l31;
        const bf16x8 vf = *(const bf16x8*)(vbase + (row * 4 + ((gn + row + (row >> 2)) & 3)) * 8);
        o[mf] = __builtin_amdgcn_mfma_f32_32x32x16_bf16(vf, pf, o[mf], 0, 0, 0);
      }
    }
    if (t + 1 < ATILES) __syncthreads();
  }
  u16* pp = part + half * PHALF + ((size_t)b * NL + q) * 256;
#pragma unroll
  for (int mf = 0; mf < 8; ++mf)
#pragma unroll
    for (int rq = 0; rq < 4; ++rq) {
      ushort4 st;
      st.x = f2bf(o[mf][rq * 4 + 0]);
      st.y = f2bf(o[mf][rq * 4 + 1]);
      st.z = f2bf(o[mf][rq * 4 + 2]);
      st.w = f2bf(o[mf][rq * 4 + 3]);
      *(ushort4*)(pp + mf * 32 + 8 * rq + 4 * lh) = st;
    }
  if (lane < 32)
    stats[((size_t)half * NB + b) * NL + q] = make_float2(m, lsum);
}

// ---------------- combine: T-layout partials -> avT bf16 + 16-chunk stats ----------------
__global__ __launch_bounds__(256)
void attn_combine(const u16* __restrict__ part, const float2* __restrict__ stats,
                  u16* __restrict__ avT, float2* __restrict__ pstat)
{
  __shared__ float2 sst[2][128];
  __shared__ float redS[8][256], redQ[8][256];
  const int chunk = blockIdx.x, b = blockIdx.y;
  const int t = threadIdx.x;
  const int rg = t >> 5;
  const int cg = (t & 31) * 8;
  const int l0 = chunk * 128;
  if (t < 128) sst[0][t] = stats[(size_t)b * NL + l0 + t];
  else sst[1][t - 128] = stats[((size_t)NB + b) * NL + l0 + (t - 128)];
  __syncthreads();
  float cs[8], cq[8];
#pragma unroll
  for (int k = 0; k < 8; ++k) { cs[k] = 0.f; cq[k] = 0.f; }
#pragma unroll 4
  for (int j = 0; j < 16; ++j) {
    const int l = j * 8 + rg;
    const float2 sa = sst[0][l], sb = sst[1][l];
    const float M = fmaxf(sa.x, sb.x);
    const float e0 = ex2(sa.x - M), e1 = ex2(sb.x - M);
    const float den = 1.f / (sa.y * e0 + sb.y * e1);
    const size_t off = ((size_t)b * NL + l0 + l) * 256 + cg;
    const bf16x8 a8 = *(const bf16x8*)(part + off);
    const bf16x8 b8 = *(const bf16x8*)(part + PHALF + off);
    u16 o8[8];
#pragma unroll
    for (int k = 0; k < 8; ++k) {
      const float r = (bf2f(((const u16*)&a8)[k]) * e0 + bf2f(((const u16*)&b8)[k]) * e1) * den;
      o8[k] = f2bf(r);
      cs[k] += r; cq[k] += r * r;
    }
    *(bf16x8*)(avT + ((size_t)b * TROWS + 1 + l0 + l) * 256 + cg) = *(bf16x8*)o8;
  }
#pragma unroll
  for (int k = 0; k < 8; ++k) { redS[rg][cg + k] = cs[k]; redQ[rg][cg + k] = cq[k]; }
  __syncthreads();
  {
    float S = 0.f, Q = 0.f;
#pragma unroll
    for (int r = 0; r < 8; ++r) { S += redS[r][t]; Q += redQ[r][t]; }
    pstat[((size_t)b * 16 + chunk) * 256 + t] = make_float2(S, Q);
  }
}

extern "C" void kernel_launch(void* const* d_in, const int* in_sizes, int n_in,
                              void* d_out, int out_size, void* d_ws, size_t ws_size,
                              hipStream_t stream)
{
  (void)in_sizes; (void)n_in; (void)out_size; (void)ws_size;
  const float* x        = (const float*)d_in[0];
  const float* t        = (const float*)d_in[1];
  const float* r1_gn1_w = (const float*)d_in[2];
  const float* r1_gn1_b = (const float*)d_in[3];
  const float* r1_c1_w  = (const float*)d_in[4];
  const float* r1_c1_b  = (const float*)d_in[5];
  const float* r1_gn2_w = (const float*)d_in[6];
  const float* r1_gn2_b = (const float*)d_in[7];
  const float* r1_c2_w  = (const float*)d_in[8];
  const float* r1_c2_b  = (const float*)d_in[9];
  const float* r2_gn1_w = (const float*)d_in[10];
  const float* r2_gn1_b = (const float*)d_in[11];
  const float* r2_c1_w  = (const float*)d_in[12];
  const float* r2_c1_b  = (const float*)d_in[13];
  const float* r2_gn2_w = (const float*)d_in[14];
  const float* r2_gn2_b = (const float*)d_in[15];
  const float* r2_c2_w  = (const float*)d_in[16];
  const float* r2_c2_b  = (const float*)d_in[17];
  const float* lin_w    = (const float*)d_in[18];
  const float* lin_b    = (const float*)d_in[19];

  float* out = (float*)d_out;

  const size_t TSZ = (size_t)NB * TROWS * 256 * 2;           // 16,793,600
  u16* tA  = (u16*)d_ws;
  u16* tB  = (u16*)((char*)d_ws + TSZ);
  u16* kq  = tB;                                             // spans [TSZ, 3TSZ)
  u16* tC  = (u16*)((char*)d_ws + 3 * TSZ);
  u16* vT  = tC;
  u16* Wp  = (u16*)((char*)d_ws + 4 * TSZ);
  u16* Wq  = Wp + 4 * 196608;
  float* bq = (float*)(Wq + 196608);
  float2* pstat = (float2*)((char*)bq + 4096);               // 512 KB
  float2* astat = (float2*)((char*)pstat + 524288);          // 512 KB attn m/lsum

  const dim3 gPack(768, 5);
  const dim3 gC(32, 1, NB);
  const dim3 gQ(64, 1, NB);
  const dim3 gS16(16, NB);
  const dim3 gA64(64, NB);
  const dim3 gCmb(16, NB);

  pack_w<<<gPack, 256, 0, stream>>>(r1_c1_w, r1_c2_w, r2_c1_w, r2_c2_w, lin_w, lin_b, Wp, Wq, bq);

  // res1
  stats_f32<<<NB * NC, 256, 0, stream>>>(x, pstat);
  apply_f32T<<<gA64, 256, 0, stream>>>(x, pstat, r1_gn1_w, r1_gn1_b, tA);
  conv_mfma<256, 3, true, 0, true><<<gC, 256, 0, stream>>>(tA, Wp, r1_c1_b, t, tB, nullptr, nullptr, nullptr, nullptr, pstat);
  apply_TT<<<gS16, 256, 0, stream>>>(tB, pstat, r1_gn2_w, r1_gn2_b, tC);
  conv_mfma<256, 3, false, 1, false><<<gC, 256, 0, stream>>>(tC, Wp + 196608, r1_c2_b, nullptr, tA, nullptr, x, nullptr, nullptr, nullptr);

  // attention
  conv_mfma<768, 1, false, 0, false><<<gQ, 256, 0, stream>>>(tA, Wq, bq, nullptr, kq, vT, nullptr, nullptr, nullptr, nullptr);
  attn_mfma<<<512, 256, 0, stream>>>(kq, vT, (u16*)out, astat);
  attn_combine<<<gCmb, 256, 0, stream>>>((const u16*)out, astat, tA, pstat);

  // res2
  apply_TT<<<gS16, 256, 0, stream>>>(tA, pstat, r2_gn1_w, r2_gn1_b, tC);
  conv_mfma<256, 3, true, 0, true><<<gC, 256, 0, stream>>>(tC, Wp + 2 * 196608, r2_c1_b, t, tB, nullptr, nullptr, nullptr, nullptr, pstat);
  apply_TT<<<gS16, 256, 0, stream>>>(tB, pstat, r2_gn2_w, r2_gn2_b, tC);
  conv_mfma<256, 3, false, 2, false><<<gC, 256, 0, stream>>>(tC, Wp + 3 * 196608, r2_c2_b, nullptr, nullptr, nullptr, nullptr, tA, out, nullptr);
}